// Round 1
// baseline (560.945 us; speedup 1.0000x reference)
//
#include <hip/hip_runtime.h>
#include <hip/hip_bf16.h>

// Problem constants
#define NB 8
#define NH 8
#define LQ 1024
#define LK 1024
#define DD 64
#define NBH 64
#define SCALE 0.125f          // 1/temperature = 1/8
#define OUT0_SIZE (8ull*8*1024*64)   // output [B,H,LQ,D]

typedef __bf16 bf16x8 __attribute__((ext_vector_type(8)));
typedef float  f32x4  __attribute__((ext_vector_type(4)));

static __device__ __forceinline__ __bf16 f2b(float f) {
    unsigned u = __builtin_bit_cast(unsigned, f);
    unsigned r = (u + 0x7fffu + ((u >> 16) & 1u)) >> 16;
    return __builtin_bit_cast(__bf16, (unsigned short)r);
}

// ---------------------------------------------------------------------------
// K0: fold weights. W[h] = WA@WB@WBt@WAt ('bcd,bdi,bim,bmj->bcj' with
// operands (W_A, W_B, W_Bt, W_At) — note the reference passes W_Bt THIRD).
// Wv[h] = Wav@Wbv. 8 blocks x 256 threads, all f32 in LDS.
// ---------------------------------------------------------------------------
__global__ void fold_weights(const float* __restrict__ pWA, const float* __restrict__ pWB,
                             const float* __restrict__ pWAt, const float* __restrict__ pWBt,
                             const float* __restrict__ pWav, const float* __restrict__ pWbv,
                             float* __restrict__ Wout, float* __restrict__ Wvout) {
    __shared__ float X[4096], Y[4096], Z[4096];
    const int h = blockIdx.x;
    const int t = threadIdx.x;

    for (int i = t; i < 4096; i += 256) { X[i] = pWA[h*4096 + i]; Y[i] = pWB[h*4096 + i]; }
    __syncthreads();
    for (int e = t; e < 4096; e += 256) {            // Z = WA @ WB
        int r = e >> 6, c = e & 63; float acc = 0.f;
        #pragma unroll
        for (int k = 0; k < 64; ++k) acc += X[r*64+k] * Y[k*64+c];
        Z[e] = acc;
    }
    __syncthreads();
    for (int i = t; i < 4096; i += 256) X[i] = pWBt[h*4096 + i];
    __syncthreads();
    for (int e = t; e < 4096; e += 256) {            // Y = Z @ WBt
        int r = e >> 6, c = e & 63; float acc = 0.f;
        #pragma unroll
        for (int k = 0; k < 64; ++k) acc += Z[r*64+k] * X[k*64+c];
        Y[e] = acc;
    }
    __syncthreads();
    for (int i = t; i < 4096; i += 256) X[i] = pWAt[h*4096 + i];
    __syncthreads();
    for (int e = t; e < 4096; e += 256) {            // W = Y @ WAt
        int r = e >> 6, c = e & 63; float acc = 0.f;
        #pragma unroll
        for (int k = 0; k < 64; ++k) acc += Y[r*64+k] * X[k*64+c];
        Wout[h*4096 + e] = acc;
    }
    __syncthreads();
    for (int i = t; i < 4096; i += 256) { X[i] = pWav[h*4096 + i]; Y[i] = pWbv[h*4096 + i]; }
    __syncthreads();
    for (int e = t; e < 4096; e += 256) {            // Wv = Wav @ Wbv
        int r = e >> 6, c = e & 63; float acc = 0.f;
        #pragma unroll
        for (int k = 0; k < 64; ++k) acc += X[r*64+k] * Y[k*64+c];
        Wvout[h*4096 + e] = acc;
    }
}

// ---------------------------------------------------------------------------
// K1: qW[bh][a][j] = sum_c q[batch,a,h,c] * W[h][c][j]   (bf16 out)
// grid (64 bh, 16 a-chunks) x 256
// ---------------------------------------------------------------------------
__global__ void qw_kernel(const float* __restrict__ q, const float* __restrict__ W,
                          __bf16* __restrict__ qW) {
    __shared__ float Wl[4096];
    __shared__ float qrows[4096];
    const int bh = blockIdx.x;
    const int a0 = blockIdx.y * 64;
    const int batch = bh >> 3, h = bh & 7;
    const int t = threadIdx.x;

    for (int i = t; i < 4096; i += 256) Wl[i] = W[h*4096 + i];
    const int cc = t & 63;
    for (int rr = t >> 6; rr < 64; rr += 4)
        qrows[rr*64 + cc] = q[(((size_t)batch*LQ + a0 + rr)*NH + h)*DD + cc];
    __syncthreads();

    const int j = t & 63;
    for (int rr = t >> 6; rr < 64; rr += 4) {
        float acc = 0.f;
        #pragma unroll
        for (int c = 0; c < 64; ++c) acc += qrows[rr*64 + c] * Wl[c*64 + j];
        qW[((size_t)bh*LQ + a0 + rr)*DD + j] = f2b(acc);
    }
}

// ---------------------------------------------------------------------------
// K2: qtT[bh][n][j] = qt[bh][j][n]  (transpose + f32->bf16)
// grid (64 bh, 8 n-chunks of 128) x 256
// ---------------------------------------------------------------------------
__global__ void qtT_kernel(const float* __restrict__ qt, __bf16* __restrict__ qtT) {
    __shared__ float tile[64][129];
    const int bh = blockIdx.x;
    const int n0 = blockIdx.y * 128;
    const int t = threadIdx.x;
    const int nl = t & 127, jh = t >> 7;
    for (int jo = 0; jo < 32; ++jo) {
        int j = jo*2 + jh;
        tile[j][nl] = qt[((size_t)bh*DD + j)*LK + n0 + nl];
    }
    __syncthreads();
    const int j = t & 63;
    for (int s = 0; s < 32; ++s) {
        int nn = (t >> 6) + 4*s;
        qtT[((size_t)bh*LK + n0 + nn)*DD + j] = f2b(tile[j][nn]);
    }
}

// ---------------------------------------------------------------------------
// K3: vWT[bh][c][m] = sum_n v[batch,m,h,n] * Wv[h][n][c]  (bf16, transposed)
// grid (64 bh, 16 m-chunks of 64) x 256
// ---------------------------------------------------------------------------
__global__ void vwT_kernel(const float* __restrict__ v, const float* __restrict__ Wv,
                           __bf16* __restrict__ vWT) {
    __shared__ float Wvl[4096];
    __shared__ float vrows[4096];
    __shared__ __bf16 res[64][72];
    const int bh = blockIdx.x;
    const int m0 = blockIdx.y * 64;
    const int batch = bh >> 3, h = bh & 7;
    const int t = threadIdx.x;

    for (int i = t; i < 4096; i += 256) Wvl[i] = Wv[h*4096 + i];
    const int nn = t & 63;
    for (int mm = t >> 6; mm < 64; mm += 4)
        vrows[mm*64 + nn] = v[(((size_t)batch*LK + m0 + mm)*NH + h)*DD + nn];
    __syncthreads();

    const int c = t & 63;
    for (int mm = t >> 6; mm < 64; mm += 4) {
        float acc = 0.f;
        #pragma unroll
        for (int n = 0; n < 64; ++n) acc += vrows[mm*64 + n] * Wvl[n*64 + c];
        res[c][mm] = f2b(acc);
    }
    __syncthreads();
    const int ml = t & 63;
    for (int co = 0; co < 16; ++co) {
        int ccc = (t >> 6) + 4*co;
        vWT[((size_t)bh*DD + ccc)*LK + m0 + ml] = res[ccc][ml];
    }
}

// ---------------------------------------------------------------------------
// K4: fused scores + softmax + attn-write + PV.
// grid 1024 (bh-major: bid>>4 = bh, bid&15 = a-tile), 256 threads = 4 waves,
// each wave owns 16 q-rows. Two passes over LK: pass1 row-sums (recompute
// is cheaper than re-reading 256MB), pass2 writes normalized attn + PV.
// ---------------------------------------------------------------------------
__global__ __launch_bounds__(256) void attn_kernel(
        const __bf16* __restrict__ qW, const __bf16* __restrict__ qtT,
        const __bf16* __restrict__ vWT, float* __restrict__ out) {
    __shared__ __align__(16) __bf16 Elds[4][16][72];   // per-wave private E tile

    const int bid = blockIdx.x;
    const int bh  = bid >> 4;
    const int a0  = (bid & 15) * 64;
    const int t   = threadIdx.x;
    const int w   = t >> 6, l = t & 63;
    const int lg  = l & 15, lq = l >> 4;
    const int arow0 = a0 + w * 16;

    // A fragments: qW rows, K=64 split into two K=32 chunks
    const bf16x8* qWp = reinterpret_cast<const bf16x8*>(qW + ((size_t)bh*LQ + arow0 + lg)*DD);
    bf16x8 afrag0 = qWp[lq];
    bf16x8 afrag1 = qWp[lq + 4];

    // ---- pass 1: row sums of exp(S) ----
    float rsum[4] = {0.f, 0.f, 0.f, 0.f};
    for (int nc = 0; nc < 64; ++nc) {
        int n = nc*16 + lg;
        const bf16x8* qtp = reinterpret_cast<const bf16x8*>(qtT + ((size_t)bh*LK + n)*DD);
        f32x4 acc = {0.f, 0.f, 0.f, 0.f};
        acc = __builtin_amdgcn_mfma_f32_16x16x32_bf16(afrag0, qtp[lq],     acc, 0, 0, 0);
        acc = __builtin_amdgcn_mfma_f32_16x16x32_bf16(afrag1, qtp[lq + 4], acc, 0, 0, 0);
        #pragma unroll
        for (int r = 0; r < 4; ++r) rsum[r] += __expf(acc[r] * SCALE);
    }
    #pragma unroll
    for (int r = 0; r < 4; ++r) {
        #pragma unroll
        for (int m = 1; m < 16; m <<= 1) rsum[r] += __shfl_xor(rsum[r], m, 16);
    }
    float rinv[4];
    #pragma unroll
    for (int r = 0; r < 4; ++r) rinv[r] = 1.0f / rsum[r];

    // ---- pass 2: normalized attn write + PV ----
    f32x4 oacc[4];
    #pragma unroll
    for (int ct = 0; ct < 4; ++ct) oacc[ct] = f32x4{0.f, 0.f, 0.f, 0.f};

    float* attn = out + OUT0_SIZE;
    for (int nc = 0; nc < 16; ++nc) {                 // 64-wide key chunks
        #pragma unroll
        for (int sub = 0; sub < 4; ++sub) {
            int n = nc*64 + sub*16 + lg;
            const bf16x8* qtp = reinterpret_cast<const bf16x8*>(qtT + ((size_t)bh*LK + n)*DD);
            f32x4 acc = {0.f, 0.f, 0.f, 0.f};
            acc = __builtin_amdgcn_mfma_f32_16x16x32_bf16(afrag0, qtp[lq],     acc, 0, 0, 0);
            acc = __builtin_amdgcn_mfma_f32_16x16x32_bf16(afrag1, qtp[lq + 4], acc, 0, 0, 0);
            #pragma unroll
            for (int r = 0; r < 4; ++r) {
                float p = __expf(acc[r] * SCALE) * rinv[r];
                int arow = arow0 + 4*lq + r;
                attn[((size_t)bh << 20) + ((size_t)arow << 10) + (size_t)n] = p;
                Elds[w][4*lq + r][sub*16 + lg] = f2b(p);
            }
        }
        // PV: O[16a][64c] += P[16a][64m] @ vWT^T ; per-wave LDS, no barrier needed
        #pragma unroll
        for (int kk = 0; kk < 2; ++kk) {
            const bf16x8* ep = reinterpret_cast<const bf16x8*>(&Elds[w][lg][0]);
            bf16x8 pf = ep[kk*4 + lq];
            #pragma unroll
            for (int ct = 0; ct < 4; ++ct) {
                int c = ct*16 + lg;
                const bf16x8* vp = reinterpret_cast<const bf16x8*>(vWT + ((size_t)bh*DD + c)*LK + nc*64);
                oacc[ct] = __builtin_amdgcn_mfma_f32_16x16x32_bf16(pf, vp[kk*4 + lq], oacc[ct], 0, 0, 0);
            }
        }
    }

    // epilogue: O (already normalized since P was normalized)
    #pragma unroll
    for (int ct = 0; ct < 4; ++ct) {
        #pragma unroll
        for (int r = 0; r < 4; ++r) {
            int arow = arow0 + 4*lq + r;
            out[(((size_t)bh*LQ + arow) << 6) + ct*16 + lg] = oacc[ct][r];
        }
    }
}

// ---------------------------------------------------------------------------
extern "C" void kernel_launch(void* const* d_in, const int* in_sizes, int n_in,
                              void* d_out, int out_size, void* d_ws, size_t ws_size,
                              hipStream_t stream) {
    const float* q   = (const float*)d_in[0];
    const float* WA  = (const float*)d_in[1];
    const float* WB  = (const float*)d_in[2];
    const float* WAt = (const float*)d_in[3];
    const float* WBt = (const float*)d_in[4];
    const float* Wav = (const float*)d_in[5];
    const float* Wbv = (const float*)d_in[6];
    const float* qt  = (const float*)d_in[7];
    const float* v   = (const float*)d_in[8];
    float* out = (float*)d_out;

    char* ws = (char*)d_ws;
    float*  W    = (float*)(ws);                          // 128 KB
    float*  Wv   = (float*)(ws + (131072));               // 128 KB
    __bf16* qW   = (__bf16*)(ws + 262144);                // 8 MB
    __bf16* qtT  = (__bf16*)(ws + 262144 + 8388608);      // 8 MB
    __bf16* vWT  = (__bf16*)(ws + 262144 + 2*8388608);    // 8 MB

    hipLaunchKernelGGL(fold_weights, dim3(8),      dim3(256), 0, stream,
                       WA, WB, WAt, WBt, Wav, Wbv, W, Wv);
    hipLaunchKernelGGL(qw_kernel,    dim3(64, 16), dim3(256), 0, stream, q,  W,  qW);
    hipLaunchKernelGGL(qtT_kernel,   dim3(64, 8),  dim3(256), 0, stream, qt, qtT);
    hipLaunchKernelGGL(vwT_kernel,   dim3(64, 16), dim3(256), 0, stream, v,  Wv, vWT);
    hipLaunchKernelGGL(attn_kernel,  dim3(1024),   dim3(256), 0, stream, qW, qtT, vWT, out);
}

// Round 2
// 240.555 us; speedup vs baseline: 2.3319x; 2.3319x over previous
//
#include <hip/hip_runtime.h>
#include <hip/hip_bf16.h>

// Problem constants
#define NB 8
#define NH 8
#define LQ 1024
#define LK 1024
#define DD 64
#define SCALE 0.125f          // 1/temperature = 1/8
#define OUT0_SIZE (8ull*8*1024*64)   // output [B,H,LQ,D]

typedef __bf16 bf16x8 __attribute__((ext_vector_type(8)));
typedef __bf16 bf16x4 __attribute__((ext_vector_type(4)));
typedef float  f32x4  __attribute__((ext_vector_type(4)));

static __device__ __forceinline__ __bf16 f2b(float f) {
    unsigned u = __builtin_bit_cast(unsigned, f);
    unsigned r = (u + 0x7fffu + ((u >> 16) & 1u)) >> 16;
    return __builtin_bit_cast(__bf16, (unsigned short)r);
}

// ---------------------------------------------------------------------------
// K0a: independent 64x64x64 f32 products: P1=WA@WB, P2=WBt@WAt, Wv=Wav@Wbv
// (associativity: W = ((WA@WB)@WBt)@WAt = (WA@WB)@(WBt@WAt)).
// grid 24 = 8 heads x 3 products. 256 threads, 4x4 register tiles,
// A staged transposed (pad 68 so float4-aligned, banks spread).
// ---------------------------------------------------------------------------
__global__ __launch_bounds__(256) void fold_pairs(
        const float* __restrict__ pWA, const float* __restrict__ pWB,
        const float* __restrict__ pWBt, const float* __restrict__ pWAt,
        const float* __restrict__ pWav, const float* __restrict__ pWbv,
        float* __restrict__ P1, float* __restrict__ P2, float* __restrict__ Wv) {
    __shared__ float AT[64*68];
    __shared__ float Bl[64*64];
    const int h = blockIdx.x / 3;
    const int which = blockIdx.x - h*3;
    const int t = threadIdx.x;
    const float *A, *B; float* C;
    if (which == 0)      { A = pWA  + h*4096; B = pWB  + h*4096; C = P1 + h*4096; }
    else if (which == 1) { A = pWBt + h*4096; B = pWAt + h*4096; C = P2 + h*4096; }
    else                 { A = pWav + h*4096; B = pWbv + h*4096; C = Wv + h*4096; }

    for (int i = t; i < 4096; i += 256) {
        int r = i >> 6, c = i & 63;
        AT[c*68 + r] = A[i];
        Bl[i] = B[i];
    }
    __syncthreads();
    const int r0 = (t >> 4) * 4, j0 = (t & 15) * 4;
    float acc[4][4] = {};
    #pragma unroll 8
    for (int k = 0; k < 64; ++k) {
        f32x4 a = *(const f32x4*)&AT[k*68 + r0];
        f32x4 b = *(const f32x4*)&Bl[k*64 + j0];
        #pragma unroll
        for (int i = 0; i < 4; ++i)
            #pragma unroll
            for (int j = 0; j < 4; ++j) acc[i][j] += a[i] * b[j];
    }
    #pragma unroll
    for (int i = 0; i < 4; ++i) {
        f32x4 o = { acc[i][0], acc[i][1], acc[i][2], acc[i][3] };
        *(f32x4*)&C[(r0 + i)*64 + j0] = o;
    }
}

// K0b: W = P1 @ P2, 8 blocks (one per head), same structure.
__global__ __launch_bounds__(256) void fold_final(
        const float* __restrict__ P1, const float* __restrict__ P2,
        float* __restrict__ Wout) {
    __shared__ float AT[64*68];
    __shared__ float Bl[64*64];
    const int h = blockIdx.x;
    const int t = threadIdx.x;
    for (int i = t; i < 4096; i += 256) {
        int r = i >> 6, c = i & 63;
        AT[c*68 + r] = P1[h*4096 + i];
        Bl[i] = P2[h*4096 + i];
    }
    __syncthreads();
    const int r0 = (t >> 4) * 4, j0 = (t & 15) * 4;
    float acc[4][4] = {};
    #pragma unroll 8
    for (int k = 0; k < 64; ++k) {
        f32x4 a = *(const f32x4*)&AT[k*68 + r0];
        f32x4 b = *(const f32x4*)&Bl[k*64 + j0];
        #pragma unroll
        for (int i = 0; i < 4; ++i)
            #pragma unroll
            for (int j = 0; j < 4; ++j) acc[i][j] += a[i] * b[j];
    }
    #pragma unroll
    for (int i = 0; i < 4; ++i) {
        f32x4 o = { acc[i][0], acc[i][1], acc[i][2], acc[i][3] };
        *(f32x4*)&Wout[h*4096 + (r0 + i)*64 + j0] = o;
    }
}

// ---------------------------------------------------------------------------
// K1: qW[bh][a][j] = sum_c q[batch,a,h,c] * W[h][c][j]   (bf16 out)
// grid (64 bh, 16 a-chunks of 64) x 256; 4x4 register tiles, float4 LDS.
// ---------------------------------------------------------------------------
__global__ __launch_bounds__(256) void qw_kernel(
        const float* __restrict__ q, const float* __restrict__ W,
        __bf16* __restrict__ qW) {
    __shared__ float qT[64*68];     // q transposed [c][r]
    __shared__ float Wl[4096];
    const int bh = blockIdx.x;
    const int a0 = blockIdx.y * 64;
    const int batch = bh >> 3, h = bh & 7;
    const int t = threadIdx.x;

    for (int i = t; i < 4096; i += 256) {
        int r = i >> 6, c = i & 63;
        Wl[i] = W[h*4096 + i];
        qT[c*68 + r] = q[(((size_t)batch*LQ + a0 + r)*NH + h)*DD + c];
    }
    __syncthreads();
    const int r0 = (t >> 4) * 4, j0 = (t & 15) * 4;
    float acc[4][4] = {};
    #pragma unroll 8
    for (int c = 0; c < 64; ++c) {
        f32x4 a = *(const f32x4*)&qT[c*68 + r0];
        f32x4 b = *(const f32x4*)&Wl[c*64 + j0];
        #pragma unroll
        for (int i = 0; i < 4; ++i)
            #pragma unroll
            for (int j = 0; j < 4; ++j) acc[i][j] += a[i] * b[j];
    }
    #pragma unroll
    for (int i = 0; i < 4; ++i) {
        bf16x4 o;
        #pragma unroll
        for (int j = 0; j < 4; ++j) o[j] = f2b(acc[i][j]);
        *(bf16x4*)&qW[((size_t)bh*LQ + a0 + r0 + i)*DD + j0] = o;
    }
}

// ---------------------------------------------------------------------------
// K2: qtT[bh][n][j] = qt[bh][j][n]  (transpose + f32->bf16)
// grid (64 bh, 8 n-chunks of 128) x 256. float4 loads, 8B bf16x4 row writes.
// ---------------------------------------------------------------------------
__global__ __launch_bounds__(256) void qtT_kernel(
        const float* __restrict__ qt, __bf16* __restrict__ qtT) {
    __shared__ float tile[64*132];
    const int bh = blockIdx.x;
    const int n0 = blockIdx.y * 128;
    const int t = threadIdx.x;
    #pragma unroll
    for (int it = 0; it < 8; ++it) {
        int idx = (t + 256*it) * 4;           // flat float index, 8192 total
        int j = idx >> 7, n = idx & 127;
        *(f32x4*)&tile[j*132 + n] = *(const f32x4*)&qt[((size_t)bh*DD + j)*LK + n0 + n];
    }
    __syncthreads();
    const int j0 = (t & 15) * 4;
    #pragma unroll
    for (int it = 0; it < 8; ++it) {
        int n = (t >> 4) + 16*it;
        bf16x4 o;
        #pragma unroll
        for (int i = 0; i < 4; ++i) o[i] = f2b(tile[(j0 + i)*132 + n]);
        *(bf16x4*)&qtT[((size_t)bh*LK + n0 + n)*DD + j0] = o;
    }
}

// ---------------------------------------------------------------------------
// K3: vWT[bh][c][m] = sum_n v[batch,m,h,n] * Wv[h][n][c]  (bf16, transposed)
// grid (64 bh, 16 m-chunks of 64) x 256. Thread tile (c0, m0) so stores are
// 16-lane x 8B contiguous per c-row.
// ---------------------------------------------------------------------------
__global__ __launch_bounds__(256) void vwT_kernel(
        const float* __restrict__ v, const float* __restrict__ Wv,
        __bf16* __restrict__ vWT) {
    __shared__ float vT[64*68];     // v transposed [n][m]
    __shared__ float Wvl[4096];
    const int bh = blockIdx.x;
    const int mb0 = blockIdx.y * 64;
    const int batch = bh >> 3, h = bh & 7;
    const int t = threadIdx.x;

    for (int i = t; i < 4096; i += 256) {
        int r = i >> 6, c = i & 63;     // r = m-row, c = n
        Wvl[i] = Wv[h*4096 + i];
        vT[c*68 + r] = v[(((size_t)batch*LK + mb0 + r)*NH + h)*DD + c];
    }
    __syncthreads();
    const int c0 = (t >> 4) * 4, m0 = (t & 15) * 4;
    float acc[4][4] = {};               // [c][m]
    #pragma unroll 8
    for (int n = 0; n < 64; ++n) {
        f32x4 wv = *(const f32x4*)&Wvl[n*64 + c0];
        f32x4 vv = *(const f32x4*)&vT[n*68 + m0];
        #pragma unroll
        for (int ci = 0; ci < 4; ++ci)
            #pragma unroll
            for (int mi = 0; mi < 4; ++mi) acc[ci][mi] += wv[ci] * vv[mi];
    }
    #pragma unroll
    for (int ci = 0; ci < 4; ++ci) {
        bf16x4 o;
        #pragma unroll
        for (int mi = 0; mi < 4; ++mi) o[mi] = f2b(acc[ci][mi]);
        *(bf16x4*)&vWT[((size_t)bh*DD + c0 + ci)*LK + mb0 + m0] = o;
    }
}

// ---------------------------------------------------------------------------
// K4: fused scores + softmax + attn-write + PV.
// XCD-aware bid mapping: xcd = bid&7 owns bh in [xcd*8, xcd*8+8) so each
// XCD's L2 holds its 8 bh's qtT+vWT slices (2 MB) across all 16 a-tiles
// and both passes. 256 threads = 4 waves, each wave owns 16 q-rows.
// ---------------------------------------------------------------------------
__global__ __launch_bounds__(256) void attn_kernel(
        const __bf16* __restrict__ qW, const __bf16* __restrict__ qtT,
        const __bf16* __restrict__ vWT, float* __restrict__ out) {
    __shared__ __align__(16) __bf16 Elds[4][16][72];   // per-wave private E tile

    const int bid = blockIdx.x;
    const int xcd = bid & 7, s = bid >> 3;
    const int bh  = xcd * 8 + (s >> 4);
    const int a0  = (s & 15) * 64;
    const int t   = threadIdx.x;
    const int w   = t >> 6, l = t & 63;
    const int lg  = l & 15, lq = l >> 4;
    const int arow0 = a0 + w * 16;

    // A fragments: qW rows, K=64 split into two K=32 chunks
    const bf16x8* qWp = reinterpret_cast<const bf16x8*>(qW + ((size_t)bh*LQ + arow0 + lg)*DD);
    bf16x8 afrag0 = qWp[lq];
    bf16x8 afrag1 = qWp[lq + 4];

    // ---- pass 1: row sums of exp(S) ----
    float rsum[4] = {0.f, 0.f, 0.f, 0.f};
    #pragma unroll 4
    for (int nc = 0; nc < 64; ++nc) {
        int n = nc*16 + lg;
        const bf16x8* qtp = reinterpret_cast<const bf16x8*>(qtT + ((size_t)bh*LK + n)*DD);
        f32x4 acc = {0.f, 0.f, 0.f, 0.f};
        acc = __builtin_amdgcn_mfma_f32_16x16x32_bf16(afrag0, qtp[lq],     acc, 0, 0, 0);
        acc = __builtin_amdgcn_mfma_f32_16x16x32_bf16(afrag1, qtp[lq + 4], acc, 0, 0, 0);
        #pragma unroll
        for (int r = 0; r < 4; ++r) rsum[r] += __expf(acc[r] * SCALE);
    }
    #pragma unroll
    for (int r = 0; r < 4; ++r) {
        #pragma unroll
        for (int m = 1; m < 16; m <<= 1) rsum[r] += __shfl_xor(rsum[r], m, 16);
    }
    float rinv[4];
    #pragma unroll
    for (int r = 0; r < 4; ++r) rinv[r] = 1.0f / rsum[r];

    // ---- pass 2: normalized attn write + PV ----
    f32x4 oacc[4];
    #pragma unroll
    for (int ct = 0; ct < 4; ++ct) oacc[ct] = f32x4{0.f, 0.f, 0.f, 0.f};

    float* attn = out + OUT0_SIZE;
    for (int nc = 0; nc < 16; ++nc) {                 // 64-wide key chunks
        #pragma unroll
        for (int sub = 0; sub < 4; ++sub) {
            int n = nc*64 + sub*16 + lg;
            const bf16x8* qtp = reinterpret_cast<const bf16x8*>(qtT + ((size_t)bh*LK + n)*DD);
            f32x4 acc = {0.f, 0.f, 0.f, 0.f};
            acc = __builtin_amdgcn_mfma_f32_16x16x32_bf16(afrag0, qtp[lq],     acc, 0, 0, 0);
            acc = __builtin_amdgcn_mfma_f32_16x16x32_bf16(afrag1, qtp[lq + 4], acc, 0, 0, 0);
            #pragma unroll
            for (int r = 0; r < 4; ++r) {
                float p = __expf(acc[r] * SCALE) * rinv[r];
                int arow = arow0 + 4*lq + r;
                attn[((size_t)bh << 20) + ((size_t)arow << 10) + (size_t)n] = p;
                Elds[w][4*lq + r][sub*16 + lg] = f2b(p);
            }
        }
        // PV: O[16a][64c] += P[16a][64m] @ vWT^T ; per-wave LDS, no barrier needed
        #pragma unroll
        for (int kk = 0; kk < 2; ++kk) {
            const bf16x8* ep = reinterpret_cast<const bf16x8*>(&Elds[w][lg][0]);
            bf16x8 pf = ep[kk*4 + lq];
            #pragma unroll
            for (int ct = 0; ct < 4; ++ct) {
                int c = ct*16 + lg;
                const bf16x8* vp = reinterpret_cast<const bf16x8*>(vWT + ((size_t)bh*DD + c)*LK + nc*64);
                oacc[ct] = __builtin_amdgcn_mfma_f32_16x16x32_bf16(pf, vp[kk*4 + lq], oacc[ct], 0, 0, 0);
            }
        }
    }

    // epilogue: O (already normalized since P was normalized)
    #pragma unroll
    for (int ct = 0; ct < 4; ++ct) {
        #pragma unroll
        for (int r = 0; r < 4; ++r) {
            int arow = arow0 + 4*lq + r;
            out[(((size_t)bh*LQ + arow) << 6) + ct*16 + lg] = oacc[ct][r];
        }
    }
}

// ---------------------------------------------------------------------------
extern "C" void kernel_launch(void* const* d_in, const int* in_sizes, int n_in,
                              void* d_out, int out_size, void* d_ws, size_t ws_size,
                              hipStream_t stream) {
    const float* q   = (const float*)d_in[0];
    const float* WA  = (const float*)d_in[1];
    const float* WB  = (const float*)d_in[2];
    const float* WAt = (const float*)d_in[3];
    const float* WBt = (const float*)d_in[4];
    const float* Wav = (const float*)d_in[5];
    const float* Wbv = (const float*)d_in[6];
    const float* qt  = (const float*)d_in[7];
    const float* v   = (const float*)d_in[8];
    float* out = (float*)d_out;

    char* ws = (char*)d_ws;
    float*  W    = (float*)(ws);                          // 128 KB
    float*  Wv   = (float*)(ws + 131072);                 // 128 KB
    __bf16* qW   = (__bf16*)(ws + 262144);                // 8 MB
    __bf16* qtT  = (__bf16*)(ws + 262144 + 8388608);      // 8 MB
    __bf16* vWT  = (__bf16*)(ws + 262144 + 2*8388608);    // 8 MB
    // P1/P2 alias the qW region: consumed by fold_final before qw_kernel writes.
    float*  P1   = (float*)(ws + 262144);                 // 128 KB
    float*  P2   = (float*)(ws + 262144 + 131072);        // 128 KB

    hipLaunchKernelGGL(fold_pairs, dim3(24), dim3(256), 0, stream,
                       WA, WB, WBt, WAt, Wav, Wbv, P1, P2, Wv);
    hipLaunchKernelGGL(fold_final, dim3(8),  dim3(256), 0, stream, P1, P2, W);
    hipLaunchKernelGGL(qw_kernel,  dim3(64, 16), dim3(256), 0, stream, q,  W,  qW);
    hipLaunchKernelGGL(qtT_kernel, dim3(64, 8),  dim3(256), 0, stream, qt, qtT);
    hipLaunchKernelGGL(vwT_kernel, dim3(64, 16), dim3(256), 0, stream, v,  Wv, vWT);
    hipLaunchKernelGGL(attn_kernel, dim3(1024),  dim3(256), 0, stream, qW, qtT, vWT, out);
}

// Round 3
// 239.564 us; speedup vs baseline: 2.3415x; 1.0041x over previous
//
#include <hip/hip_runtime.h>
#include <hip/hip_bf16.h>

// Problem constants
#define NB 8
#define NH 8
#define LQ 1024
#define LK 1024
#define DD 64
#define SCALE 0.125f          // 1/temperature = 1/8
#define OUT0_SIZE (8ull*8*1024*64)   // output [B,H,LQ,D]

typedef __bf16 bf16x8 __attribute__((ext_vector_type(8)));
typedef __bf16 bf16x4 __attribute__((ext_vector_type(4)));
typedef float  f32x4  __attribute__((ext_vector_type(4)));

static __device__ __forceinline__ __bf16 f2b(float f) {
    unsigned u = __builtin_bit_cast(unsigned, f);
    unsigned r = (u + 0x7fffu + ((u >> 16) & 1u)) >> 16;
    return __builtin_bit_cast(__bf16, (unsigned short)r);
}

// ---------------------------------------------------------------------------
// K0a: independent 64x64x64 f32 products: P1=WA@WB, P2=WBt@WAt, Wv=Wav@Wbv
// ---------------------------------------------------------------------------
__global__ __launch_bounds__(256) void fold_pairs(
        const float* __restrict__ pWA, const float* __restrict__ pWB,
        const float* __restrict__ pWBt, const float* __restrict__ pWAt,
        const float* __restrict__ pWav, const float* __restrict__ pWbv,
        float* __restrict__ P1, float* __restrict__ P2, float* __restrict__ Wv) {
    __shared__ float AT[64*68];
    __shared__ float Bl[64*64];
    const int h = blockIdx.x / 3;
    const int which = blockIdx.x - h*3;
    const int t = threadIdx.x;
    const float *A, *B; float* C;
    if (which == 0)      { A = pWA  + h*4096; B = pWB  + h*4096; C = P1 + h*4096; }
    else if (which == 1) { A = pWBt + h*4096; B = pWAt + h*4096; C = P2 + h*4096; }
    else                 { A = pWav + h*4096; B = pWbv + h*4096; C = Wv + h*4096; }

    for (int i = t; i < 4096; i += 256) {
        int r = i >> 6, c = i & 63;
        AT[c*68 + r] = A[i];
        Bl[i] = B[i];
    }
    __syncthreads();
    const int r0 = (t >> 4) * 4, j0 = (t & 15) * 4;
    float acc[4][4] = {};
    #pragma unroll 8
    for (int k = 0; k < 64; ++k) {
        f32x4 a = *(const f32x4*)&AT[k*68 + r0];
        f32x4 b = *(const f32x4*)&Bl[k*64 + j0];
        #pragma unroll
        for (int i = 0; i < 4; ++i)
            #pragma unroll
            for (int j = 0; j < 4; ++j) acc[i][j] += a[i] * b[j];
    }
    #pragma unroll
    for (int i = 0; i < 4; ++i) {
        f32x4 o = { acc[i][0], acc[i][1], acc[i][2], acc[i][3] };
        *(f32x4*)&C[(r0 + i)*64 + j0] = o;
    }
}

// K0b: W = P1 @ P2, 8 blocks (one per head)
__global__ __launch_bounds__(256) void fold_final(
        const float* __restrict__ P1, const float* __restrict__ P2,
        float* __restrict__ Wout) {
    __shared__ float AT[64*68];
    __shared__ float Bl[64*64];
    const int h = blockIdx.x;
    const int t = threadIdx.x;
    for (int i = t; i < 4096; i += 256) {
        int r = i >> 6, c = i & 63;
        AT[c*68 + r] = P1[h*4096 + i];
        Bl[i] = P2[h*4096 + i];
    }
    __syncthreads();
    const int r0 = (t >> 4) * 4, j0 = (t & 15) * 4;
    float acc[4][4] = {};
    #pragma unroll 8
    for (int k = 0; k < 64; ++k) {
        f32x4 a = *(const f32x4*)&AT[k*68 + r0];
        f32x4 b = *(const f32x4*)&Bl[k*64 + j0];
        #pragma unroll
        for (int i = 0; i < 4; ++i)
            #pragma unroll
            for (int j = 0; j < 4; ++j) acc[i][j] += a[i] * b[j];
    }
    #pragma unroll
    for (int i = 0; i < 4; ++i) {
        f32x4 o = { acc[i][0], acc[i][1], acc[i][2], acc[i][3] };
        *(f32x4*)&Wout[h*4096 + (r0 + i)*64 + j0] = o;
    }
}

// ---------------------------------------------------------------------------
// K1: qW[bh][a][j] = sum_c q[batch,a,h,c] * W[h][c][j]   (bf16 out)
// ---------------------------------------------------------------------------
__global__ __launch_bounds__(256) void qw_kernel(
        const float* __restrict__ q, const float* __restrict__ W,
        __bf16* __restrict__ qW) {
    __shared__ float qT[64*68];     // q transposed [c][r]
    __shared__ float Wl[4096];
    const int bh = blockIdx.x;
    const int a0 = blockIdx.y * 64;
    const int batch = bh >> 3, h = bh & 7;
    const int t = threadIdx.x;

    for (int i = t; i < 4096; i += 256) {
        int r = i >> 6, c = i & 63;
        Wl[i] = W[h*4096 + i];
        qT[c*68 + r] = q[(((size_t)batch*LQ + a0 + r)*NH + h)*DD + c];
    }
    __syncthreads();
    const int r0 = (t >> 4) * 4, j0 = (t & 15) * 4;
    float acc[4][4] = {};
    #pragma unroll 8
    for (int c = 0; c < 64; ++c) {
        f32x4 a = *(const f32x4*)&qT[c*68 + r0];
        f32x4 b = *(const f32x4*)&Wl[c*64 + j0];
        #pragma unroll
        for (int i = 0; i < 4; ++i)
            #pragma unroll
            for (int j = 0; j < 4; ++j) acc[i][j] += a[i] * b[j];
    }
    #pragma unroll
    for (int i = 0; i < 4; ++i) {
        bf16x4 o;
        #pragma unroll
        for (int j = 0; j < 4; ++j) o[j] = f2b(acc[i][j]);
        *(bf16x4*)&qW[((size_t)bh*LQ + a0 + r0 + i)*DD + j0] = o;
    }
}

// ---------------------------------------------------------------------------
// K2: qtT[bh][n][j] = qt[bh][j][n]  (transpose + f32->bf16)
// ---------------------------------------------------------------------------
__global__ __launch_bounds__(256) void qtT_kernel(
        const float* __restrict__ qt, __bf16* __restrict__ qtT) {
    __shared__ float tile[64*132];
    const int bh = blockIdx.x;
    const int n0 = blockIdx.y * 128;
    const int t = threadIdx.x;
    #pragma unroll
    for (int it = 0; it < 8; ++it) {
        int idx = (t + 256*it) * 4;           // flat float index, 8192 total
        int j = idx >> 7, n = idx & 127;
        *(f32x4*)&tile[j*132 + n] = *(const f32x4*)&qt[((size_t)bh*DD + j)*LK + n0 + n];
    }
    __syncthreads();
    const int j0 = (t & 15) * 4;
    #pragma unroll
    for (int it = 0; it < 8; ++it) {
        int n = (t >> 4) + 16*it;
        bf16x4 o;
        #pragma unroll
        for (int i = 0; i < 4; ++i) o[i] = f2b(tile[(j0 + i)*132 + n]);
        *(bf16x4*)&qtT[((size_t)bh*LK + n0 + n)*DD + j0] = o;
    }
}

// ---------------------------------------------------------------------------
// K3: vWT[bh][c][m] = sum_n v[batch,m,h,n] * Wv[h][n][c]  (bf16, transposed)
// ---------------------------------------------------------------------------
__global__ __launch_bounds__(256) void vwT_kernel(
        const float* __restrict__ v, const float* __restrict__ Wv,
        __bf16* __restrict__ vWT) {
    __shared__ float vT[64*68];     // v transposed [n][m]
    __shared__ float Wvl[4096];
    const int bh = blockIdx.x;
    const int mb0 = blockIdx.y * 64;
    const int batch = bh >> 3, h = bh & 7;
    const int t = threadIdx.x;

    for (int i = t; i < 4096; i += 256) {
        int r = i >> 6, c = i & 63;     // r = m-row, c = n
        Wvl[i] = Wv[h*4096 + i];
        vT[c*68 + r] = v[(((size_t)batch*LK + mb0 + r)*NH + h)*DD + c];
    }
    __syncthreads();
    const int c0 = (t >> 4) * 4, m0 = (t & 15) * 4;
    float acc[4][4] = {};               // [c][m]
    #pragma unroll 8
    for (int n = 0; n < 64; ++n) {
        f32x4 wv = *(const f32x4*)&Wvl[n*64 + c0];
        f32x4 vv = *(const f32x4*)&vT[n*68 + m0];
        #pragma unroll
        for (int ci = 0; ci < 4; ++ci)
            #pragma unroll
            for (int mi = 0; mi < 4; ++mi) acc[ci][mi] += wv[ci] * vv[mi];
    }
    #pragma unroll
    for (int ci = 0; ci < 4; ++ci) {
        bf16x4 o;
        #pragma unroll
        for (int mi = 0; mi < 4; ++mi) o[mi] = f2b(acc[ci][mi]);
        *(bf16x4*)&vWT[((size_t)bh*DD + c0 + ci)*LK + mb0 + m0] = o;
    }
}

// ---------------------------------------------------------------------------
// K4: fused scores + softmax + attn-write + PV, operand-swapped MFMAs.
// Grid 2048: xcd = bid&7 owns 8 bh (L2 locality); per block: 32 q-rows,
// 4 waves = 2 row-strips x 2 n-halves (512 keys each). 8 blocks/CU.
// Swapped QK (A=qtT, B=qW): lane holds S[n..n+3][q] -> f32x4 attn stores.
// Swapped PV (A=vWT, B=P):  lane holds O[q][c..c+3]  -> f32x4 out stores.
// ---------------------------------------------------------------------------
__global__ __launch_bounds__(256, 8) void attn_kernel(
        const __bf16* __restrict__ qW, const __bf16* __restrict__ qtT,
        const __bf16* __restrict__ vWT, float* __restrict__ out) {
    __shared__ __align__(16) __bf16 Elds[4][16][72];   // per-wave P tile (bf16)
    __shared__ __align__(16) float  Obuf[2][16][68];   // per-strip O partial (from nh=1)
    __shared__ float rsumbuf[2][2][16];                // [nh][strip][q]

    const int bid = blockIdx.x;
    const int xcd = bid & 7, s = bid >> 3;
    const int bh  = xcd * 8 + (s >> 5);
    const int a0  = (s & 31) * 32;
    const int t   = threadIdx.x;
    const int w   = t >> 6, l = t & 63;
    const int lg  = l & 15, g = l >> 4;
    const int strip = w & 1, nh = w >> 1;
    const int qbase = a0 + strip * 16;
    const int n0w   = nh * 512;

    // B fragments (N = q): lane holds qW[qbase+lg][g*8 .. +7] (+32 for k-hi)
    const bf16x8* qWp = reinterpret_cast<const bf16x8*>(qW + ((size_t)bh*LQ + qbase + lg)*DD);
    bf16x8 bfrag0 = qWp[g];
    bf16x8 bfrag1 = qWp[g + 4];

    // ---- pass 1: per-q row sums of exp(S) over this wave's 512 keys ----
    float rsum = 0.f;
    #pragma unroll 4
    for (int nc = 0; nc < 32; ++nc) {
        int n = n0w + nc*16 + lg;
        const bf16x8* qtp = reinterpret_cast<const bf16x8*>(qtT + ((size_t)bh*LK + n)*DD);
        f32x4 acc = {0.f, 0.f, 0.f, 0.f};
        acc = __builtin_amdgcn_mfma_f32_16x16x32_bf16(qtp[g],     bfrag0, acc, 0, 0, 0);
        acc = __builtin_amdgcn_mfma_f32_16x16x32_bf16(qtp[g + 4], bfrag1, acc, 0, 0, 0);
        #pragma unroll
        for (int r = 0; r < 4; ++r) rsum += __expf(acc[r] * SCALE);
    }
    rsum += __shfl_xor(rsum, 16);
    rsum += __shfl_xor(rsum, 32);
    if (l < 16) rsumbuf[nh][strip][l] = rsum;
    __syncthreads();
    const float rinv = 1.0f / (rsumbuf[0][strip][lg] + rsumbuf[1][strip][lg]);

    // ---- pass 2: normalized attn write (f32x4) + PV ----
    f32x4 oacc[4];
    #pragma unroll
    for (int ct = 0; ct < 4; ++ct) oacc[ct] = f32x4{0.f, 0.f, 0.f, 0.f};

    float* attn = out + OUT0_SIZE;
    for (int nc = 0; nc < 8; ++nc) {                 // 64-key chunks
        const int nbase = n0w + nc*64;
        #pragma unroll
        for (int sub = 0; sub < 4; ++sub) {
            int n = nbase + sub*16 + lg;
            const bf16x8* qtp = reinterpret_cast<const bf16x8*>(qtT + ((size_t)bh*LK + n)*DD);
            f32x4 acc = {0.f, 0.f, 0.f, 0.f};
            acc = __builtin_amdgcn_mfma_f32_16x16x32_bf16(qtp[g],     bfrag0, acc, 0, 0, 0);
            acc = __builtin_amdgcn_mfma_f32_16x16x32_bf16(qtp[g + 4], bfrag1, acc, 0, 0, 0);
            f32x4 p; bf16x4 pb;
            #pragma unroll
            for (int r = 0; r < 4; ++r) {
                p[r] = __expf(acc[r] * SCALE) * rinv;
                pb[r] = f2b(p[r]);
            }
            // lane: q = qbase+lg, n = nbase + sub*16 + 4g .. +3 (contiguous)
            *(f32x4*)&attn[((size_t)bh << 20) + ((size_t)(qbase + lg) << 10) + nbase + sub*16 + g*4] = p;
            *(bf16x4*)&Elds[w][lg][sub*16 + g*4] = pb;
        }
        // PV: A = vWT (M=c), B = P^T fragment (N=q) from Elds
        #pragma unroll
        for (int kk = 0; kk < 2; ++kk) {
            const bf16x8* ep = reinterpret_cast<const bf16x8*>(&Elds[w][lg][0]);
            bf16x8 pf = ep[kk*4 + g];
            #pragma unroll
            for (int ct = 0; ct < 4; ++ct) {
                const bf16x8* vp = reinterpret_cast<const bf16x8*>(vWT + ((size_t)bh*DD + ct*16 + lg)*LK + nbase);
                oacc[ct] = __builtin_amdgcn_mfma_f32_16x16x32_bf16(vp[kk*4 + g], pf, oacc[ct], 0, 0, 0);
            }
        }
    }

    // ---- cross-wave O reduction (n-halves) + store ----
    if (nh == 1) {
        #pragma unroll
        for (int ct = 0; ct < 4; ++ct)
            *(f32x4*)&Obuf[strip][lg][ct*16 + g*4] = oacc[ct];
    }
    __syncthreads();
    if (nh == 0) {
        #pragma unroll
        for (int ct = 0; ct < 4; ++ct) {
            f32x4 o = *(const f32x4*)&Obuf[strip][lg][ct*16 + g*4];
            o = o + oacc[ct];
            // lane: q = qbase+lg, c = ct*16 + 4g .. +3 (contiguous)
            *(f32x4*)&out[(((size_t)bh*LQ + qbase + lg) << 6) + ct*16 + g*4] = o;
        }
    }
}

// ---------------------------------------------------------------------------
extern "C" void kernel_launch(void* const* d_in, const int* in_sizes, int n_in,
                              void* d_out, int out_size, void* d_ws, size_t ws_size,
                              hipStream_t stream) {
    const float* q   = (const float*)d_in[0];
    const float* WA  = (const float*)d_in[1];
    const float* WB  = (const float*)d_in[2];
    const float* WAt = (const float*)d_in[3];
    const float* WBt = (const float*)d_in[4];
    const float* Wav = (const float*)d_in[5];
    const float* Wbv = (const float*)d_in[6];
    const float* qt  = (const float*)d_in[7];
    const float* v   = (const float*)d_in[8];
    float* out = (float*)d_out;

    char* ws = (char*)d_ws;
    float*  W    = (float*)(ws);                          // 128 KB
    float*  Wv   = (float*)(ws + 131072);                 // 128 KB
    __bf16* qW   = (__bf16*)(ws + 262144);                // 8 MB
    __bf16* qtT  = (__bf16*)(ws + 262144 + 8388608);      // 8 MB
    __bf16* vWT  = (__bf16*)(ws + 262144 + 2*8388608);    // 8 MB
    // P1/P2 alias the qW region: consumed by fold_final before qw_kernel writes.
    float*  P1   = (float*)(ws + 262144);                 // 128 KB
    float*  P2   = (float*)(ws + 262144 + 131072);        // 128 KB

    hipLaunchKernelGGL(fold_pairs, dim3(24), dim3(256), 0, stream,
                       WA, WB, WBt, WAt, Wav, Wbv, P1, P2, Wv);
    hipLaunchKernelGGL(fold_final, dim3(8),  dim3(256), 0, stream, P1, P2, W);
    hipLaunchKernelGGL(qw_kernel,  dim3(64, 16), dim3(256), 0, stream, q,  W,  qW);
    hipLaunchKernelGGL(qtT_kernel, dim3(64, 8),  dim3(256), 0, stream, qt, qtT);
    hipLaunchKernelGGL(vwT_kernel, dim3(64, 16), dim3(256), 0, stream, v,  Wv, vWT);
    hipLaunchKernelGGL(attn_kernel, dim3(2048),  dim3(256), 0, stream, qW, qtT, vWT, out);
}

// Round 4
// 222.095 us; speedup vs baseline: 2.5257x; 1.0787x over previous
//
#include <hip/hip_runtime.h>
#include <hip/hip_bf16.h>

// Problem constants
#define NB 8
#define NH 8
#define LQ 1024
#define LK 1024
#define DD 64
#define EC 0.18033688011112042f      // (1/8) * log2(e)
#define OUT0_SIZE (8ull*8*1024*64)   // output [B,H,LQ,D]

typedef __bf16 bf16x8 __attribute__((ext_vector_type(8)));
typedef __bf16 bf16x4 __attribute__((ext_vector_type(4)));
typedef float  f32x4  __attribute__((ext_vector_type(4)));

static __device__ __forceinline__ __bf16 f2b(float f) {
    unsigned u = __builtin_bit_cast(unsigned, f);
    unsigned r = (u + 0x7fffu + ((u >> 16) & 1u)) >> 16;
    return __builtin_bit_cast(__bf16, (unsigned short)r);
}

// ---------------------------------------------------------------------------
// K0a: independent 64x64x64 f32 products: P1=WA@WB, P2=WBt@WAt, Wv=Wav@Wbv
// ---------------------------------------------------------------------------
__global__ __launch_bounds__(256) void fold_pairs(
        const float* __restrict__ pWA, const float* __restrict__ pWB,
        const float* __restrict__ pWBt, const float* __restrict__ pWAt,
        const float* __restrict__ pWav, const float* __restrict__ pWbv,
        float* __restrict__ P1, float* __restrict__ P2, float* __restrict__ Wv) {
    __shared__ float AT[64*68];
    __shared__ float Bl[64*64];
    const int h = blockIdx.x / 3;
    const int which = blockIdx.x - h*3;
    const int t = threadIdx.x;
    const float *A, *B; float* C;
    if (which == 0)      { A = pWA  + h*4096; B = pWB  + h*4096; C = P1 + h*4096; }
    else if (which == 1) { A = pWBt + h*4096; B = pWAt + h*4096; C = P2 + h*4096; }
    else                 { A = pWav + h*4096; B = pWbv + h*4096; C = Wv + h*4096; }

    for (int i = t; i < 4096; i += 256) {
        int r = i >> 6, c = i & 63;
        AT[c*68 + r] = A[i];
        Bl[i] = B[i];
    }
    __syncthreads();
    const int r0 = (t >> 4) * 4, j0 = (t & 15) * 4;
    float acc[4][4] = {};
    #pragma unroll 8
    for (int k = 0; k < 64; ++k) {
        f32x4 a = *(const f32x4*)&AT[k*68 + r0];
        f32x4 b = *(const f32x4*)&Bl[k*64 + j0];
        #pragma unroll
        for (int i = 0; i < 4; ++i)
            #pragma unroll
            for (int j = 0; j < 4; ++j) acc[i][j] += a[i] * b[j];
    }
    #pragma unroll
    for (int i = 0; i < 4; ++i) {
        f32x4 o = { acc[i][0], acc[i][1], acc[i][2], acc[i][3] };
        *(f32x4*)&C[(r0 + i)*64 + j0] = o;
    }
}

// K0b: W = P1 @ P2, 8 blocks (one per head)
__global__ __launch_bounds__(256) void fold_final(
        const float* __restrict__ P1, const float* __restrict__ P2,
        float* __restrict__ Wout) {
    __shared__ float AT[64*68];
    __shared__ float Bl[64*64];
    const int h = blockIdx.x;
    const int t = threadIdx.x;
    for (int i = t; i < 4096; i += 256) {
        int r = i >> 6, c = i & 63;
        AT[c*68 + r] = P1[h*4096 + i];
        Bl[i] = P2[h*4096 + i];
    }
    __syncthreads();
    const int r0 = (t >> 4) * 4, j0 = (t & 15) * 4;
    float acc[4][4] = {};
    #pragma unroll 8
    for (int k = 0; k < 64; ++k) {
        f32x4 a = *(const f32x4*)&AT[k*68 + r0];
        f32x4 b = *(const f32x4*)&Bl[k*64 + j0];
        #pragma unroll
        for (int i = 0; i < 4; ++i)
            #pragma unroll
            for (int j = 0; j < 4; ++j) acc[i][j] += a[i] * b[j];
    }
    #pragma unroll
    for (int i = 0; i < 4; ++i) {
        f32x4 o = { acc[i][0], acc[i][1], acc[i][2], acc[i][3] };
        *(f32x4*)&Wout[h*4096 + (r0 + i)*64 + j0] = o;
    }
}

// ---------------------------------------------------------------------------
// K1 (merged prepass): blockIdx.y selects
//   [0,16):  qW[bh][a][j]  = sum_c q[b,a,h,c] * W[h][c][j]       (64-row chunk)
//   [16,24): qtT[bh][n][j] = qt[bh][j][n]                         (128-n chunk)
//   [24,40): vWT[bh][c][m] = sum_n v[b,m,h,n] * Wv[h][n][c]       (64-m chunk)
// ---------------------------------------------------------------------------
__global__ __launch_bounds__(256) void prepass(
        const float* __restrict__ q, const float* __restrict__ W,
        const float* __restrict__ qt, const float* __restrict__ v,
        const float* __restrict__ Wv,
        __bf16* __restrict__ qW, __bf16* __restrict__ qtT,
        __bf16* __restrict__ vWT) {
    __shared__ float smem[8448];
    const int bh = blockIdx.x;
    const int by = blockIdx.y;
    const int batch = bh >> 3, h = bh & 7;
    const int t = threadIdx.x;

    if (by < 16) {
        float* qT = smem;            // [c][r] 64x68
        float* Wl = smem + 4352;     // [c][j] 64x64
        const int a0 = by * 64;
        for (int i = t; i < 4096; i += 256) {
            int r = i >> 6, c = i & 63;
            Wl[i] = W[h*4096 + i];
            qT[c*68 + r] = q[(((size_t)batch*LQ + a0 + r)*NH + h)*DD + c];
        }
        __syncthreads();
        const int r0 = (t >> 4) * 4, j0 = (t & 15) * 4;
        float acc[4][4] = {};
        #pragma unroll 8
        for (int c = 0; c < 64; ++c) {
            f32x4 a = *(const f32x4*)&qT[c*68 + r0];
            f32x4 b = *(const f32x4*)&Wl[c*64 + j0];
            #pragma unroll
            for (int i = 0; i < 4; ++i)
                #pragma unroll
                for (int j = 0; j < 4; ++j) acc[i][j] += a[i] * b[j];
        }
        #pragma unroll
        for (int i = 0; i < 4; ++i) {
            bf16x4 o;
            #pragma unroll
            for (int j = 0; j < 4; ++j) o[j] = f2b(acc[i][j]);
            *(bf16x4*)&qW[((size_t)bh*LQ + a0 + r0 + i)*DD + j0] = o;
        }
    } else if (by < 24) {
        float* tile = smem;          // [j][n] 64x132
        const int n0 = (by - 16) * 128;
        #pragma unroll
        for (int it = 0; it < 8; ++it) {
            int idx = (t + 256*it) * 4;
            int j = idx >> 7, n = idx & 127;
            *(f32x4*)&tile[j*132 + n] = *(const f32x4*)&qt[((size_t)bh*DD + j)*LK + n0 + n];
        }
        __syncthreads();
        const int j0 = (t & 15) * 4;
        #pragma unroll
        for (int it = 0; it < 8; ++it) {
            int n = (t >> 4) + 16*it;
            bf16x4 o;
            #pragma unroll
            for (int i = 0; i < 4; ++i) o[i] = f2b(tile[(j0 + i)*132 + n]);
            *(bf16x4*)&qtT[((size_t)bh*LK + n0 + n)*DD + j0] = o;
        }
    } else {
        float* vT  = smem;           // [n][m] 64x68
        float* Wvl = smem + 4352;    // [n][c] 64x64
        const int mb0 = (by - 24) * 64;
        for (int i = t; i < 4096; i += 256) {
            int r = i >> 6, c = i & 63;     // r = m-row, c = n
            Wvl[i] = Wv[h*4096 + i];
            vT[c*68 + r] = v[(((size_t)batch*LK + mb0 + r)*NH + h)*DD + c];
        }
        __syncthreads();
        const int c0 = (t >> 4) * 4, m0 = (t & 15) * 4;
        float acc[4][4] = {};               // [c][m]
        #pragma unroll 8
        for (int n = 0; n < 64; ++n) {
            f32x4 wv = *(const f32x4*)&Wvl[n*64 + c0];
            f32x4 vv = *(const f32x4*)&vT[n*68 + m0];
            #pragma unroll
            for (int ci = 0; ci < 4; ++ci)
                #pragma unroll
                for (int mi = 0; mi < 4; ++mi) acc[ci][mi] += wv[ci] * vv[mi];
        }
        #pragma unroll
        for (int ci = 0; ci < 4; ++ci) {
            bf16x4 o;
            #pragma unroll
            for (int mi = 0; mi < 4; ++mi) o[mi] = f2b(acc[ci][mi]);
            *(bf16x4*)&vWT[((size_t)bh*DD + c0 + ci)*LK + mb0 + m0] = o;
        }
    }
}

// ---------------------------------------------------------------------------
// K4: fused scores + softmax + attn-write + PV. Swapped-operand MFMAs.
// Store-path discipline: per 64-key chunk, batch compute into regs; issue
// NEXT chunk's loads BEFORE this chunk's stores (loads older than stores in
// the vmcnt FIFO -> load-waits never drain stores). Nontemporal stores for
// the attn/out streams (never re-read; avoid L2/L3 allocate+thrash).
// ---------------------------------------------------------------------------
__global__ __launch_bounds__(256, 3) void attn_kernel(
        const __bf16* __restrict__ qW, const __bf16* __restrict__ qtT,
        const __bf16* __restrict__ vWT, float* __restrict__ out) {
    __shared__ __align__(16) __bf16 Elds[4][16][72];   // per-wave P tile (bf16)
    __shared__ __align__(16) float  Obuf[2][16][68];   // per-strip O partial
    __shared__ float rsumbuf[2][2][16];                // [nh][strip][q]

    const int bid = blockIdx.x;
    const int xcd = bid & 7, s = bid >> 3;
    const int bh  = xcd * 8 + (s >> 5);
    const int a0  = (s & 31) * 32;
    const int t   = threadIdx.x;
    const int w   = t >> 6, l = t & 63;
    const int lg  = l & 15, g = l >> 4;
    const int strip = w & 1, nh = w >> 1;
    const int qbase = a0 + strip * 16;
    const int n0w   = nh * 512;

    const __bf16* qtb = qtT + (size_t)bh * LK * DD;
    const __bf16* vwb = vWT + (size_t)bh * DD * LK;

    // B fragments (N = q): lane holds qW[qbase+lg][g*8 .. +7] (+32 for k-hi)
    const bf16x8* qWp = reinterpret_cast<const bf16x8*>(qW + ((size_t)bh*LQ + qbase + lg)*DD);
    bf16x8 bfrag0 = qWp[g];
    bf16x8 bfrag1 = qWp[g + 4];

    // ---- pass 1: per-q row sums of exp(S) over this wave's 512 keys ----
    bf16x8 ka[4][2];
    #pragma unroll
    for (int sub = 0; sub < 4; ++sub) {
        const bf16x8* qtp = (const bf16x8*)(qtb + (size_t)(n0w + sub*16 + lg)*DD);
        ka[sub][0] = qtp[g]; ka[sub][1] = qtp[g + 4];
    }
    float rsum = 0.f;
    #pragma unroll
    for (int nc = 0; nc < 8; ++nc) {
        f32x4 accs[4];
        #pragma unroll
        for (int sub = 0; sub < 4; ++sub) {
            f32x4 acc = {0.f, 0.f, 0.f, 0.f};
            acc = __builtin_amdgcn_mfma_f32_16x16x32_bf16(ka[sub][0], bfrag0, acc, 0, 0, 0);
            acc = __builtin_amdgcn_mfma_f32_16x16x32_bf16(ka[sub][1], bfrag1, acc, 0, 0, 0);
            accs[sub] = acc;
        }
        if (nc < 7) {
            #pragma unroll
            for (int sub = 0; sub < 4; ++sub) {
                const bf16x8* qtp = (const bf16x8*)(qtb + (size_t)(n0w + (nc+1)*64 + sub*16 + lg)*DD);
                ka[sub][0] = qtp[g]; ka[sub][1] = qtp[g + 4];
            }
        }
        #pragma unroll
        for (int sub = 0; sub < 4; ++sub)
            #pragma unroll
            for (int r = 0; r < 4; ++r) rsum += __builtin_exp2f(accs[sub][r] * EC);
    }
    rsum += __shfl_xor(rsum, 16);
    rsum += __shfl_xor(rsum, 32);
    if (l < 16) rsumbuf[nh][strip][l] = rsum;
    __syncthreads();
    const float rinv = 1.0f / (rsumbuf[0][strip][lg] + rsumbuf[1][strip][lg]);

    // ---- pass 2: normalized attn write (NT f32x4) + PV ----
    #pragma unroll
    for (int sub = 0; sub < 4; ++sub) {
        const bf16x8* qtp = (const bf16x8*)(qtb + (size_t)(n0w + sub*16 + lg)*DD);
        ka[sub][0] = qtp[g]; ka[sub][1] = qtp[g + 4];
    }
    bf16x8 vp0[4], vp1[4];
    #pragma unroll
    for (int ct = 0; ct < 4; ++ct) {
        const bf16x8* vpp = (const bf16x8*)(vwb + (size_t)(ct*16 + lg)*LK + n0w);
        vp0[ct] = vpp[g]; vp1[ct] = vpp[4 + g];
    }

    f32x4 oacc[4];
    #pragma unroll
    for (int ct = 0; ct < 4; ++ct) oacc[ct] = f32x4{0.f, 0.f, 0.f, 0.f};

    float* attnb = out + OUT0_SIZE + ((size_t)bh << 20) + ((size_t)(qbase + lg) << 10);

    #pragma unroll
    for (int nc = 0; nc < 8; ++nc) {
        const int nbase = n0w + nc*64;
        f32x4 p[4];
        #pragma unroll
        for (int sub = 0; sub < 4; ++sub) {
            f32x4 acc = {0.f, 0.f, 0.f, 0.f};
            acc = __builtin_amdgcn_mfma_f32_16x16x32_bf16(ka[sub][0], bfrag0, acc, 0, 0, 0);
            acc = __builtin_amdgcn_mfma_f32_16x16x32_bf16(ka[sub][1], bfrag1, acc, 0, 0, 0);
            bf16x4 pb;
            #pragma unroll
            for (int r = 0; r < 4; ++r) {
                float pv_ = __builtin_exp2f(acc[r] * EC) * rinv;
                p[sub][r] = pv_;
                pb[r] = f2b(pv_);
            }
            *(bf16x4*)&Elds[w][lg][sub*16 + g*4] = pb;
        }
        // prefetch next chunk's QK fragments (loads issued BEFORE stores)
        if (nc < 7) {
            #pragma unroll
            for (int sub = 0; sub < 4; ++sub) {
                const bf16x8* qtp = (const bf16x8*)(qtb + (size_t)(nbase + 64 + sub*16 + lg)*DD);
                ka[sub][0] = qtp[g]; ka[sub][1] = qtp[g + 4];
            }
        }
        // PV with current (prefetched) vWT fragments
        bf16x8 pf0 = ((const bf16x8*)&Elds[w][lg][0])[g];
        bf16x8 pf1 = ((const bf16x8*)&Elds[w][lg][0])[4 + g];
        #pragma unroll
        for (int ct = 0; ct < 4; ++ct) {
            oacc[ct] = __builtin_amdgcn_mfma_f32_16x16x32_bf16(vp0[ct], pf0, oacc[ct], 0, 0, 0);
            oacc[ct] = __builtin_amdgcn_mfma_f32_16x16x32_bf16(vp1[ct], pf1, oacc[ct], 0, 0, 0);
        }
        if (nc < 7) {
            #pragma unroll
            for (int ct = 0; ct < 4; ++ct) {
                const bf16x8* vpp = (const bf16x8*)(vwb + (size_t)(ct*16 + lg)*LK + nbase + 64);
                vp0[ct] = vpp[g]; vp1[ct] = vpp[4 + g];
            }
        }
        // NT stores, issued last in the iteration
        #pragma unroll
        for (int sub = 0; sub < 4; ++sub)
            __builtin_nontemporal_store(p[sub], (f32x4*)&attnb[nbase + sub*16 + g*4]);
    }

    // ---- cross-wave O reduction (n-halves) + NT store ----
    if (nh == 1) {
        #pragma unroll
        for (int ct = 0; ct < 4; ++ct)
            *(f32x4*)&Obuf[strip][lg][ct*16 + g*4] = oacc[ct];
    }
    __syncthreads();
    if (nh == 0) {
        #pragma unroll
        for (int ct = 0; ct < 4; ++ct) {
            f32x4 o = *(const f32x4*)&Obuf[strip][lg][ct*16 + g*4];
            o = o + oacc[ct];
            __builtin_nontemporal_store(o,
                (f32x4*)&out[(((size_t)bh*LQ + qbase + lg) << 6) + ct*16 + g*4]);
        }
    }
}

// ---------------------------------------------------------------------------
extern "C" void kernel_launch(void* const* d_in, const int* in_sizes, int n_in,
                              void* d_out, int out_size, void* d_ws, size_t ws_size,
                              hipStream_t stream) {
    const float* q   = (const float*)d_in[0];
    const float* WA  = (const float*)d_in[1];
    const float* WB  = (const float*)d_in[2];
    const float* WAt = (const float*)d_in[3];
    const float* WBt = (const float*)d_in[4];
    const float* Wav = (const float*)d_in[5];
    const float* Wbv = (const float*)d_in[6];
    const float* qt  = (const float*)d_in[7];
    const float* v   = (const float*)d_in[8];
    float* out = (float*)d_out;

    char* ws = (char*)d_ws;
    float*  W    = (float*)(ws);                          // 128 KB
    float*  Wv   = (float*)(ws + 131072);                 // 128 KB
    __bf16* qW   = (__bf16*)(ws + 262144);                // 8 MB
    __bf16* qtT  = (__bf16*)(ws + 262144 + 8388608);      // 8 MB
    __bf16* vWT  = (__bf16*)(ws + 262144 + 2*8388608);    // 8 MB
    // P1/P2 alias the qW region: consumed by fold_final before prepass writes.
    float*  P1   = (float*)(ws + 262144);                 // 128 KB
    float*  P2   = (float*)(ws + 262144 + 131072);        // 128 KB

    hipLaunchKernelGGL(fold_pairs, dim3(24), dim3(256), 0, stream,
                       WA, WB, WBt, WAt, Wav, Wbv, P1, P2, Wv);
    hipLaunchKernelGGL(fold_final, dim3(8),  dim3(256), 0, stream, P1, P2, W);
    hipLaunchKernelGGL(prepass,    dim3(64, 40), dim3(256), 0, stream,
                       q, W, qt, v, Wv, qW, qtT, vWT);
    hipLaunchKernelGGL(attn_kernel, dim3(2048), dim3(256), 0, stream, qW, qtT, vWT, out);
}

// Round 5
// 213.391 us; speedup vs baseline: 2.6287x; 1.0408x over previous
//
#include <hip/hip_runtime.h>
#include <hip/hip_bf16.h>

// Problem constants
#define NB 8
#define NH 8
#define LQ 1024
#define LK 1024
#define DD 64
#define EC 0.18033688011112042f      // (1/8) * log2(e)
#define OUT0_SIZE (8ull*8*1024*64)   // output [B,H,LQ,D]

typedef __bf16 bf16x8 __attribute__((ext_vector_type(8)));
typedef __bf16 bf16x4 __attribute__((ext_vector_type(4)));
typedef float  f32x4  __attribute__((ext_vector_type(4)));

static __device__ __forceinline__ __bf16 f2b(float f) {
    unsigned u = __builtin_bit_cast(unsigned, f);
    unsigned r = (u + 0x7fffu + ((u >> 16) & 1u)) >> 16;
    return __builtin_bit_cast(__bf16, (unsigned short)r);
}

// ---------------------------------------------------------------------------
// K0a: independent 64x64x64 f32 products: P1=WA@WB, P2=WBt@WAt, Wv=Wav@Wbv
// ---------------------------------------------------------------------------
__global__ __launch_bounds__(256) void fold_pairs(
        const float* __restrict__ pWA, const float* __restrict__ pWB,
        const float* __restrict__ pWBt, const float* __restrict__ pWAt,
        const float* __restrict__ pWav, const float* __restrict__ pWbv,
        float* __restrict__ P1, float* __restrict__ P2, float* __restrict__ Wv) {
    __shared__ float AT[64*68];
    __shared__ float Bl[64*64];
    const int h = blockIdx.x / 3;
    const int which = blockIdx.x - h*3;
    const int t = threadIdx.x;
    const float *A, *B; float* C;
    if (which == 0)      { A = pWA  + h*4096; B = pWB  + h*4096; C = P1 + h*4096; }
    else if (which == 1) { A = pWBt + h*4096; B = pWAt + h*4096; C = P2 + h*4096; }
    else                 { A = pWav + h*4096; B = pWbv + h*4096; C = Wv + h*4096; }

    for (int i = t; i < 4096; i += 256) {
        int r = i >> 6, c = i & 63;
        AT[c*68 + r] = A[i];
        Bl[i] = B[i];
    }
    __syncthreads();
    const int r0 = (t >> 4) * 4, j0 = (t & 15) * 4;
    float acc[4][4] = {};
    #pragma unroll 8
    for (int k = 0; k < 64; ++k) {
        f32x4 a = *(const f32x4*)&AT[k*68 + r0];
        f32x4 b = *(const f32x4*)&Bl[k*64 + j0];
        #pragma unroll
        for (int i = 0; i < 4; ++i)
            #pragma unroll
            for (int j = 0; j < 4; ++j) acc[i][j] += a[i] * b[j];
    }
    #pragma unroll
    for (int i = 0; i < 4; ++i) {
        f32x4 o = { acc[i][0], acc[i][1], acc[i][2], acc[i][3] };
        *(f32x4*)&C[(r0 + i)*64 + j0] = o;
    }
}

// K0b: W = P1 @ P2, 8 blocks (one per head)
__global__ __launch_bounds__(256) void fold_final(
        const float* __restrict__ P1, const float* __restrict__ P2,
        float* __restrict__ Wout) {
    __shared__ float AT[64*68];
    __shared__ float Bl[64*64];
    const int h = blockIdx.x;
    const int t = threadIdx.x;
    for (int i = t; i < 4096; i += 256) {
        int r = i >> 6, c = i & 63;
        AT[c*68 + r] = P1[h*4096 + i];
        Bl[i] = P2[h*4096 + i];
    }
    __syncthreads();
    const int r0 = (t >> 4) * 4, j0 = (t & 15) * 4;
    float acc[4][4] = {};
    #pragma unroll 8
    for (int k = 0; k < 64; ++k) {
        f32x4 a = *(const f32x4*)&AT[k*68 + r0];
        f32x4 b = *(const f32x4*)&Bl[k*64 + j0];
        #pragma unroll
        for (int i = 0; i < 4; ++i)
            #pragma unroll
            for (int j = 0; j < 4; ++j) acc[i][j] += a[i] * b[j];
    }
    #pragma unroll
    for (int i = 0; i < 4; ++i) {
        f32x4 o = { acc[i][0], acc[i][1], acc[i][2], acc[i][3] };
        *(f32x4*)&Wout[h*4096 + (r0 + i)*64 + j0] = o;
    }
}

// ---------------------------------------------------------------------------
// K1 (merged prepass): blockIdx.y selects
//   [0,16):  qW[bh][a][j]  = sum_c q[b,a,h,c] * W[h][c][j]       (64-row chunk)
//   [16,24): qtT[bh][n][j] = qt[bh][j][n]                         (128-n chunk)
//   [24,40): vWT[bh][c][m] = sum_n v[b,m,h,n] * Wv[h][n][c]       (64-m chunk)
// ---------------------------------------------------------------------------
__global__ __launch_bounds__(256) void prepass(
        const float* __restrict__ q, const float* __restrict__ W,
        const float* __restrict__ qt, const float* __restrict__ v,
        const float* __restrict__ Wv,
        __bf16* __restrict__ qW, __bf16* __restrict__ qtT,
        __bf16* __restrict__ vWT) {
    __shared__ float smem[8448];
    const int bh = blockIdx.x;
    const int by = blockIdx.y;
    const int batch = bh >> 3, h = bh & 7;
    const int t = threadIdx.x;

    if (by < 16) {
        float* qT = smem;            // [c][r] 64x68
        float* Wl = smem + 4352;     // [c][j] 64x64
        const int a0 = by * 64;
        for (int i = t; i < 4096; i += 256) {
            int r = i >> 6, c = i & 63;
            Wl[i] = W[h*4096 + i];
            qT[c*68 + r] = q[(((size_t)batch*LQ + a0 + r)*NH + h)*DD + c];
        }
        __syncthreads();
        const int r0 = (t >> 4) * 4, j0 = (t & 15) * 4;
        float acc[4][4] = {};
        #pragma unroll 8
        for (int c = 0; c < 64; ++c) {
            f32x4 a = *(const f32x4*)&qT[c*68 + r0];
            f32x4 b = *(const f32x4*)&Wl[c*64 + j0];
            #pragma unroll
            for (int i = 0; i < 4; ++i)
                #pragma unroll
                for (int j = 0; j < 4; ++j) acc[i][j] += a[i] * b[j];
        }
        #pragma unroll
        for (int i = 0; i < 4; ++i) {
            bf16x4 o;
            #pragma unroll
            for (int j = 0; j < 4; ++j) o[j] = f2b(acc[i][j]);
            *(bf16x4*)&qW[((size_t)bh*LQ + a0 + r0 + i)*DD + j0] = o;
        }
    } else if (by < 24) {
        float* tile = smem;          // [j][n] 64x132
        const int n0 = (by - 16) * 128;
        #pragma unroll
        for (int it = 0; it < 8; ++it) {
            int idx = (t + 256*it) * 4;
            int j = idx >> 7, n = idx & 127;
            *(f32x4*)&tile[j*132 + n] = *(const f32x4*)&qt[((size_t)bh*DD + j)*LK + n0 + n];
        }
        __syncthreads();
        const int j0 = (t & 15) * 4;
        #pragma unroll
        for (int it = 0; it < 8; ++it) {
            int n = (t >> 4) + 16*it;
            bf16x4 o;
            #pragma unroll
            for (int i = 0; i < 4; ++i) o[i] = f2b(tile[(j0 + i)*132 + n]);
            *(bf16x4*)&qtT[((size_t)bh*LK + n0 + n)*DD + j0] = o;
        }
    } else {
        float* vT  = smem;           // [n][m] 64x68
        float* Wvl = smem + 4352;    // [n][c] 64x64
        const int mb0 = (by - 24) * 64;
        for (int i = t; i < 4096; i += 256) {
            int r = i >> 6, c = i & 63;     // r = m-row, c = n
            Wvl[i] = Wv[h*4096 + i];
            vT[c*68 + r] = v[(((size_t)batch*LK + mb0 + r)*NH + h)*DD + c];
        }
        __syncthreads();
        const int c0 = (t >> 4) * 4, m0 = (t & 15) * 4;
        float acc[4][4] = {};               // [c][m]
        #pragma unroll 8
        for (int n = 0; n < 64; ++n) {
            f32x4 wv = *(const f32x4*)&Wvl[n*64 + c0];
            f32x4 vv = *(const f32x4*)&vT[n*68 + m0];
            #pragma unroll
            for (int ci = 0; ci < 4; ++ci)
                #pragma unroll
                for (int mi = 0; mi < 4; ++mi) acc[ci][mi] += wv[ci] * vv[mi];
        }
        #pragma unroll
        for (int ci = 0; ci < 4; ++ci) {
            bf16x4 o;
            #pragma unroll
            for (int mi = 0; mi < 4; ++mi) o[mi] = f2b(acc[ci][mi]);
            *(bf16x4*)&vWT[((size_t)bh*DD + c0 + ci)*LK + mb0 + m0] = o;
        }
    }
}

// ---------------------------------------------------------------------------
// K4: fused scores + softmax + attn-write + PV.
// Store-pattern fix: P and O are staged through LDS and stored with a
// lane-contiguous mapping -> each store instruction covers 4 rows x 256B
// CONTIGUOUS segments (vs 16 rows x 64B scattered before). Loads are still
// issued before stores each iteration (vmcnt FIFO discipline).
// ---------------------------------------------------------------------------
__global__ __launch_bounds__(256) void attn_kernel(
        const __bf16* __restrict__ qW, const __bf16* __restrict__ qtT,
        const __bf16* __restrict__ vWT, float* __restrict__ out) {
    __shared__ __align__(16) __bf16 Elds[4][16][72];   // per-wave P tile (bf16, PV operand)
    __shared__ __align__(16) float  Pt[4][16][68];     // per-wave P tile (f32, store staging)
    __shared__ __align__(16) float  Obuf[32][68];      // block O tile (f32)
    __shared__ float rsumbuf[2][2][16];                // [nh][strip][q]

    const int bid = blockIdx.x;
    const int xcd = bid & 7, s = bid >> 3;
    const int bh  = xcd * 8 + (s >> 5);
    const int a0  = (s & 31) * 32;
    const int t   = threadIdx.x;
    const int w   = t >> 6, l = t & 63;
    const int lg  = l & 15, g = l >> 4;
    const int strip = w & 1, nh = w >> 1;
    const int qbase = a0 + strip * 16;
    const int n0w   = nh * 512;

    const __bf16* qtb = qtT + (size_t)bh * LK * DD;
    const __bf16* vwb = vWT + (size_t)bh * DD * LK;

    // B fragments (N = q): lane holds qW[qbase+lg][g*8 .. +7] (+32 for k-hi)
    const bf16x8* qWp = reinterpret_cast<const bf16x8*>(qW + ((size_t)bh*LQ + qbase + lg)*DD);
    bf16x8 bfrag0 = qWp[g];
    bf16x8 bfrag1 = qWp[g + 4];

    // ---- pass 1: per-q row sums of exp(S) over this wave's 512 keys ----
    bf16x8 ka[4][2];
    #pragma unroll
    for (int sub = 0; sub < 4; ++sub) {
        const bf16x8* qtp = (const bf16x8*)(qtb + (size_t)(n0w + sub*16 + lg)*DD);
        ka[sub][0] = qtp[g]; ka[sub][1] = qtp[g + 4];
    }
    float rsum = 0.f;
    #pragma unroll
    for (int nc = 0; nc < 8; ++nc) {
        f32x4 accs[4];
        #pragma unroll
        for (int sub = 0; sub < 4; ++sub) {
            f32x4 acc = {0.f, 0.f, 0.f, 0.f};
            acc = __builtin_amdgcn_mfma_f32_16x16x32_bf16(ka[sub][0], bfrag0, acc, 0, 0, 0);
            acc = __builtin_amdgcn_mfma_f32_16x16x32_bf16(ka[sub][1], bfrag1, acc, 0, 0, 0);
            accs[sub] = acc;
        }
        if (nc < 7) {
            #pragma unroll
            for (int sub = 0; sub < 4; ++sub) {
                const bf16x8* qtp = (const bf16x8*)(qtb + (size_t)(n0w + (nc+1)*64 + sub*16 + lg)*DD);
                ka[sub][0] = qtp[g]; ka[sub][1] = qtp[g + 4];
            }
        }
        #pragma unroll
        for (int sub = 0; sub < 4; ++sub)
            #pragma unroll
            for (int r = 0; r < 4; ++r) rsum += __builtin_exp2f(accs[sub][r] * EC);
    }
    rsum += __shfl_xor(rsum, 16);
    rsum += __shfl_xor(rsum, 32);
    if (l < 16) rsumbuf[nh][strip][l] = rsum;
    __syncthreads();
    const float rinv = 1.0f / (rsumbuf[0][strip][lg] + rsumbuf[1][strip][lg]);

    // ---- pass 2: P compute + LDS-staged contiguous attn stores + PV ----
    #pragma unroll
    for (int sub = 0; sub < 4; ++sub) {
        const bf16x8* qtp = (const bf16x8*)(qtb + (size_t)(n0w + sub*16 + lg)*DD);
        ka[sub][0] = qtp[g]; ka[sub][1] = qtp[g + 4];
    }
    bf16x8 vp0[4], vp1[4];
    #pragma unroll
    for (int ct = 0; ct < 4; ++ct) {
        const bf16x8* vpp = (const bf16x8*)(vwb + (size_t)(ct*16 + lg)*LK + n0w);
        vp0[ct] = vpp[g]; vp1[ct] = vpp[4 + g];
    }

    f32x4 oacc[4];
    #pragma unroll
    for (int ct = 0; ct < 4; ++ct) oacc[ct] = f32x4{0.f, 0.f, 0.f, 0.f};

    float* attnb = out + OUT0_SIZE + ((size_t)bh << 20);
    const int rr = l >> 4, cc = l & 15;    // store-phase lane mapping

    #pragma unroll
    for (int nc = 0; nc < 8; ++nc) {
        const int nbase = n0w + nc*64;
        #pragma unroll
        for (int sub = 0; sub < 4; ++sub) {
            f32x4 acc = {0.f, 0.f, 0.f, 0.f};
            acc = __builtin_amdgcn_mfma_f32_16x16x32_bf16(ka[sub][0], bfrag0, acc, 0, 0, 0);
            acc = __builtin_amdgcn_mfma_f32_16x16x32_bf16(ka[sub][1], bfrag1, acc, 0, 0, 0);
            f32x4 p; bf16x4 pb;
            #pragma unroll
            for (int r = 0; r < 4; ++r) {
                float pv_ = __builtin_exp2f(acc[r] * EC) * rinv;
                p[r] = pv_;
                pb[r] = f2b(pv_);
            }
            *(f32x4*)&Pt[w][lg][sub*16 + g*4] = p;
            *(bf16x4*)&Elds[w][lg][sub*16 + g*4] = pb;
        }
        // prefetch next chunk's QK fragments (loads issued BEFORE stores)
        if (nc < 7) {
            #pragma unroll
            for (int sub = 0; sub < 4; ++sub) {
                const bf16x8* qtp = (const bf16x8*)(qtb + (size_t)(nbase + 64 + sub*16 + lg)*DD);
                ka[sub][0] = qtp[g]; ka[sub][1] = qtp[g + 4];
            }
        }
        // PV with current (prefetched) vWT fragments
        bf16x8 pf0 = ((const bf16x8*)&Elds[w][lg][0])[g];
        bf16x8 pf1 = ((const bf16x8*)&Elds[w][lg][0])[4 + g];
        #pragma unroll
        for (int ct = 0; ct < 4; ++ct) {
            oacc[ct] = __builtin_amdgcn_mfma_f32_16x16x32_bf16(vp0[ct], pf0, oacc[ct], 0, 0, 0);
            oacc[ct] = __builtin_amdgcn_mfma_f32_16x16x32_bf16(vp1[ct], pf1, oacc[ct], 0, 0, 0);
        }
        if (nc < 7) {
            #pragma unroll
            for (int ct = 0; ct < 4; ++ct) {
                const bf16x8* vpp = (const bf16x8*)(vwb + (size_t)(ct*16 + lg)*LK + nbase + 64);
                vp0[ct] = vpp[g]; vp1[ct] = vpp[4 + g];
            }
        }
        // contiguous NT store phase: 4 instructions, each 4 rows x 256B segments
        #pragma unroll
        for (int it = 0; it < 4; ++it) {
            int row = it*4 + rr;
            f32x4 p = *(const f32x4*)&Pt[w][row][cc*4];
            __builtin_nontemporal_store(p,
                (f32x4*)&attnb[((size_t)(qbase + row) << 10) + nbase + cc*4]);
        }
    }

    // ---- cross-wave O reduction in LDS + contiguous NT store ----
    if (nh == 1) {
        #pragma unroll
        for (int ct = 0; ct < 4; ++ct)
            *(f32x4*)&Obuf[strip*16 + lg][ct*16 + g*4] = oacc[ct];
    }
    __syncthreads();
    if (nh == 0) {
        #pragma unroll
        for (int ct = 0; ct < 4; ++ct) {
            f32x4 o = *(const f32x4*)&Obuf[strip*16 + lg][ct*16 + g*4];
            o = o + oacc[ct];
            *(f32x4*)&Obuf[strip*16 + lg][ct*16 + g*4] = o;
        }
    }
    __syncthreads();
    #pragma unroll
    for (int it = 0; it < 2; ++it) {
        int row = it*16 + w*4 + rr;           // 0..31
        f32x4 o = *(const f32x4*)&Obuf[row][cc*4];
        __builtin_nontemporal_store(o,
            (f32x4*)&out[(((size_t)bh*LQ + a0 + row) << 6) + cc*4]);
    }
}

// ---------------------------------------------------------------------------
extern "C" void kernel_launch(void* const* d_in, const int* in_sizes, int n_in,
                              void* d_out, int out_size, void* d_ws, size_t ws_size,
                              hipStream_t stream) {
    const float* q   = (const float*)d_in[0];
    const float* WA  = (const float*)d_in[1];
    const float* WB  = (const float*)d_in[2];
    const float* WAt = (const float*)d_in[3];
    const float* WBt = (const float*)d_in[4];
    const float* Wav = (const float*)d_in[5];
    const float* Wbv = (const float*)d_in[6];
    const float* qt  = (const float*)d_in[7];
    const float* v   = (const float*)d_in[8];
    float* out = (float*)d_out;

    char* ws = (char*)d_ws;
    float*  W    = (float*)(ws);                          // 128 KB
    float*  Wv   = (float*)(ws + 131072);                 // 128 KB
    __bf16* qW   = (__bf16*)(ws + 262144);                // 8 MB
    __bf16* qtT  = (__bf16*)(ws + 262144 + 8388608);      // 8 MB
    __bf16* vWT  = (__bf16*)(ws + 262144 + 2*8388608);    // 8 MB
    // P1/P2 alias the qW region: consumed by fold_final before prepass writes.
    float*  P1   = (float*)(ws + 262144);                 // 128 KB
    float*  P2   = (float*)(ws + 262144 + 131072);        // 128 KB

    hipLaunchKernelGGL(fold_pairs, dim3(24), dim3(256), 0, stream,
                       WA, WB, WBt, WAt, Wav, Wbv, P1, P2, Wv);
    hipLaunchKernelGGL(fold_final, dim3(8),  dim3(256), 0, stream, P1, P2, W);
    hipLaunchKernelGGL(prepass,    dim3(64, 40), dim3(256), 0, stream,
                       q, W, qt, v, Wv, qW, qtT, vWT);
    hipLaunchKernelGGL(attn_kernel, dim3(2048), dim3(256), 0, stream, qW, qtT, vWT, out);
}